// Round 12
// baseline (250.686 us; speedup 1.0000x reference)
//
#include <hip/hip_runtime.h>
#include <hip/hip_bf16.h>

// ---------------------------------------------------------------------------
// RRN forward, MI355X.  3 dispatches: kP -> k2 -> k4.
//   kP: fused prep, 61 blocks x 1024 threads (4 jobs/block, 4 waves/SIMD):
//       jobs 0-115 frag-pack f16 hi/lo weights; jobs 116-243 projections + S=0.
//   k2: pairwise MLP (FROZEN round 10/11: 62us plateau).
//   k4: fused MFMA tail, 32 blocks x 1024 threads (16 waves = 4/SIMD for
//       latency hiding); CAT gates staged via LDS, math identical to round 5.
// ---------------------------------------------------------------------------

#define NN   512
#define HH   128
#define F1D  256
#define F2D  256
#define OUTD 64
#define ICHUNK 64

typedef _Float16 half_t;
typedef _Float16 half8 __attribute__((ext_vector_type(8)));
typedef float float4_t __attribute__((ext_vector_type(4)));
typedef float float8_t __attribute__((ext_vector_type(8)));

__device__ __forceinline__ float sigmoidf_(float x) {
    return 1.0f / (1.0f + __expf(-x));
}

#define HL_INV 2.44140625e-4f

// ---- workspace layout (bytes) ----
// A32 0 (512K) | B32 524288 (512K) | W2H 1048576 (128K) | W2L 1179648 (128K)
// S 1310720 (512K) | tail 1835008..3342336 (1.507M)
#define WS_TAIL_B 1835008
// f16-element offsets within tail region (hi base; lo = hi + cnt):
#define T3H 0
#define G1H 65536
#define G2H 196608
#define G3H 327680
#define CATH 393216
#define O1H 655360
#define O2H 720896

// ---------------- kP: fused prep (61 blocks x 1024 threads, 4 jobs/block) ----------------
__constant__ int p_cum[8]   = {16, 24, 40, 56, 64, 96, 112, 116};
__constant__ int p_K[8]     = {256, 256, 256, 256, 256, 256, 128, 256};
__constant__ int p_hioff[8] = {0, T3H, G1H, G2H, G3H, CATH, O1H, O2H};
__constant__ int p_cnt[8]   = {65536, 32768, 65536, 65536, 32768, 131072, 32768, 16384};

__global__ __launch_bounds__(1024)
void kP_prep(const float* __restrict__ hidden,
             const float* __restrict__ Wf1,
             const float* __restrict__ bf1,
             const float* __restrict__ Wf2,
             const float* __restrict__ Wf3,
             const float* __restrict__ Wg1, const float* __restrict__ Wg2,
             const float* __restrict__ Wg3,
             const float* __restrict__ W_ih, const float* __restrict__ W_hh,
             const float* __restrict__ Wo1, const float* __restrict__ Wo2,
             half_t* __restrict__ tail,
             half_t* __restrict__ W2H, half_t* __restrict__ W2L,
             float* __restrict__ A32, float* __restrict__ B32,
             float* __restrict__ S) {
    __shared__ float slab[4][4096];
    const int tid = threadIdx.x;
    const int sub = tid >> 8;          // 0..3: which job in this block
    const int t = tid & 255;
    const int jb = blockIdx.x * 4 + sub;   // 0..243
    float* mySlab = slab[sub];

    if (jb < 116) {
        // ---- weight frag-pack job ----
        int m = 0;
        while (m < 7 && jb >= p_cum[m]) ++m;
        const int pl = jb - (m ? p_cum[m - 1] : 0);
        const int K = p_K[m];
        const int kshift = (K == 256) ? 8 : 7;
        const int n0 = pl * 16;

        const float* src;
        switch (m) {
            case 0: src = Wf2; break;
            case 1: src = Wf3; break;
            case 2: src = Wg1; break;
            case 3: src = Wg2; break;
            case 4: src = Wg3; break;
            case 6: src = Wo1; break;
            default: src = Wo2; break;  // m==7 ; m==5 handled below
        }
        for (int q = t; q < (16 * K) / 4; q += 256) {
            const int flat = q * 4;
            const int r = flat >> kshift;
            const int k = flat & (K - 1);
            float4_t v;
            if (m == 5) {
                v = (k < 128) ? *(const float4_t*)(W_ih + (n0 + r) * 128 + k)
                              : *(const float4_t*)(W_hh + (n0 + r) * 128 + (k - 128));
            } else {
                v = *(const float4_t*)(src + (size_t)(n0 + r) * K + k);
            }
            *(float4_t*)&mySlab[flat] = v;
        }
        __syncthreads();

        half_t *hi, *lo;
        if (m == 0) { hi = W2H; lo = W2L; }
        else        { hi = tail + p_hioff[m]; lo = hi + p_cnt[m]; }
        const int base = pl * (K << 4);
        for (int f0 = t * 8; f0 < 16 * K; f0 += 2048) {
            const int ks = f0 >> 9;
            const int g4 = (f0 >> 7) & 3;
            const int l15 = (f0 >> 3) & 15;
            const int k0 = ks * 32 + g4 * 8;
            float8_t v = *(const float8_t*)&mySlab[l15 * K + k0];
            half8 hv, lv;
#pragma unroll
            for (int e = 0; e < 8; ++e) {
                half_t h = (half_t)v[e];
                hv[e] = h;
                lv[e] = (half_t)((v[e] - (float)h) * 4096.0f);
            }
            *(half8*)(hi + base + f0) = hv;
            *(half8*)(lo + base + f0) = lv;
        }
    } else {
        // ---- projection job (round-2-verified math) + S zeroing ----
        const int pb = jb - 116;           // 0..127
        const int i0 = pb * 4;

        {
            float4_t z = {0.0f, 0.0f, 0.0f, 0.0f};
            *(float4_t*)(S + (size_t)pb * 1024 + t * 4) = z;
        }

        float* hid = mySlab;               // [4][128]
        for (int q = t; q < 4 * HH; q += 256)
            hid[q] = hidden[i0 * HH + q];
        __syncthreads();

        float accA[4], accB[4];
        const float b = bf1[t];
#pragma unroll
        for (int r = 0; r < 4; ++r) { accA[r] = b; accB[r] = 0.0f; }

        const float* wr = Wf1 + t * 256;
#pragma unroll 4
        for (int k = 0; k < HH; k += 4) {
            float4_t wa = *(const float4_t*)(wr + k);
            float4_t wb = *(const float4_t*)(wr + HH + k);
#pragma unroll
            for (int r = 0; r < 4; ++r) {
                const float* hp = &hid[r * HH + k];
                accA[r] += wa[0]*hp[0] + wa[1]*hp[1] + wa[2]*hp[2] + wa[3]*hp[3];
                accB[r] += wb[0]*hp[0] + wb[1]*hp[1] + wb[2]*hp[2] + wb[3]*hp[3];
            }
        }
#pragma unroll
        for (int r = 0; r < 4; ++r) {
            A32[(i0 + r) * F1D + t] = accA[r];
            B32[(i0 + r) * F1D + t] = accB[r];
        }
    }
}

// ---------------- k2: pairwise MLP (FROZEN, round 10) ----------------
__global__ __launch_bounds__(512, 2)
void k2_pairwise(const float* __restrict__ A32,
                 const float* __restrict__ B32,
                 const half_t* __restrict__ W2H,
                 const half_t* __restrict__ W2L,
                 const float* __restrict__ bf2,
                 float* __restrict__ S) {
    __shared__ half_t hbuf[2][4][8][512];   // 64 KB

    const int tid = threadIdx.x;
    const int lane = tid & 63;
    const int w = tid >> 6;           // wave 0..7
    const int l15 = lane & 15;
    const int g4 = lane >> 4;         // 0..3
    const int j0 = blockIdx.y * 16;
    const int i0 = blockIdx.x * ICHUNK;
    const int lane8 = lane * 8;

    const half8* WH8 = (const half8*)W2H;
    const half8* WL8 = (const half8*)W2L;
    half8 Wh[2][8], Wl[2][8];
#pragma unroll
    for (int nt = 0; nt < 2; ++nt)
#pragma unroll
        for (int ks = 0; ks < 8; ++ks) {
            const int idx = (w * 2 + nt) * 512 + ks * 64 + lane;
            Wh[nt][ks] = WH8[idx];
            Wl[nt][ks] = WL8[idx];
        }
#pragma unroll
    for (int nt = 0; nt < 2; ++nt)
#pragma unroll
        for (int ks = 0; ks < 8; ++ks) {
            asm volatile("" : "+v"(Wh[nt][ks]));
            asm volatile("" : "+v"(Wl[nt][ks]));
        }

    float4_t Bw0 = *(const float4_t*)(B32 + (size_t)(j0 + l15) * F1D + w * 32 + g4 * 8);
    float4_t Bw1 = *(const float4_t*)(B32 + (size_t)(j0 + l15) * F1D + w * 32 + g4 * 8 + 4);

    float b2v[2];
#pragma unroll
    for (int nt = 0; nt < 2; ++nt) b2v[nt] = bf2[w * 32 + nt * 16 + l15];

    float4_t acc[2];
#pragma unroll
    for (int nt = 0; nt < 2; ++nt)
#pragma unroll
        for (int r = 0; r < 4; ++r) acc[nt][r] = 0.0f;

#pragma unroll
    for (int q = 0; q < 4; ++q) {
        const float* Ap = A32 + (size_t)(i0 + q) * F1D + w * 32 + g4 * 8;
        float4_t a0 = *(const float4_t*)Ap;
        float4_t a1 = *(const float4_t*)(Ap + 4);
        half8 hf;
#pragma unroll
        for (int e = 0; e < 4; ++e) {
            hf[e]     = (half_t)fmaxf(a0[e] + Bw0[e], 0.0f);
            hf[4 + e] = (half_t)fmaxf(a1[e] + Bw1[e], 0.0f);
        }
        *(half8*)&hbuf[0][q][w][lane8] = hf;
    }
    __syncthreads();

    for (int c = 0; c < 16; ++c) {
        const int cur = c & 1;
        const int nxt = cur ^ 1;
        const int ibase = i0 + (c + 1) * 4;

#pragma unroll
        for (int q = 0; q < 4; ++q) {
            float4_t a0, a1;
            if (c < 15) {
                const float* Ap = A32 + (size_t)(ibase + q) * F1D + w * 32 + g4 * 8;
                a0 = *(const float4_t*)Ap;
                a1 = *(const float4_t*)(Ap + 4);
            }

            float4_t C[2], Cl[2];
#pragma unroll
            for (int nt = 0; nt < 2; ++nt)
#pragma unroll
                for (int r = 0; r < 4; ++r) { C[nt][r] = 0.0f; Cl[nt][r] = 0.0f; }
#pragma unroll
            for (int ks = 0; ks < 8; ++ks) {
                half8 hf = *(const half8*)&hbuf[cur][q][ks][lane8];
                C[0]  = __builtin_amdgcn_mfma_f32_16x16x32_f16(hf, Wh[0][ks], C[0], 0, 0, 0);
                C[1]  = __builtin_amdgcn_mfma_f32_16x16x32_f16(hf, Wh[1][ks], C[1], 0, 0, 0);
                Cl[0] = __builtin_amdgcn_mfma_f32_16x16x32_f16(hf, Wl[0][ks], Cl[0], 0, 0, 0);
                Cl[1] = __builtin_amdgcn_mfma_f32_16x16x32_f16(hf, Wl[1][ks], Cl[1], 0, 0, 0);
            }

            if (c < 15) {
                half8 hf;
#pragma unroll
                for (int e = 0; e < 4; ++e) {
                    hf[e]     = (half_t)fmaxf(a0[e] + Bw0[e], 0.0f);
                    hf[4 + e] = (half_t)fmaxf(a1[e] + Bw1[e], 0.0f);
                }
                *(half8*)&hbuf[nxt][q][w][lane8] = hf;
            }

#pragma unroll
            for (int nt = 0; nt < 2; ++nt)
#pragma unroll
                for (int r = 0; r < 4; ++r) {
                    float v = fmaf(Cl[nt][r], HL_INV, C[nt][r]) + b2v[nt];
                    acc[nt][r] += fmaxf(v, 0.0f);
                }
        }
        __syncthreads();
    }

#pragma unroll
    for (int nt = 0; nt < 2; ++nt)
#pragma unroll
        for (int r = 0; r < 4; ++r)
            atomicAdd(&S[(size_t)(j0 + g4 * 4 + r) * F2D + w * 32 + nt * 16 + l15], acc[nt][r]);
}

// ---------------- k4: fused MFMA tail, 16 waves ----------------
#define AST 260   // LDS activation row stride (floats)

template<int NT, int NKS>
__device__ __forceinline__ void frag_gemm(const float* __restrict__ aPtr,
                                          const half_t* __restrict__ WhF,
                                          const half_t* __restrict__ WlF,
                                          const int* pB, int lane8,
                                          float4_t* Chi, float4_t* Clo) {
#pragma unroll
    for (int ks = 0; ks < NKS; ++ks) {
        float4_t a0 = *(const float4_t*)(aPtr + ks * 32);
        float4_t a1 = *(const float4_t*)(aPtr + ks * 32 + 4);
        half8 ah, al;
#pragma unroll
        for (int e = 0; e < 4; ++e) {
            half_t h0 = (half_t)a0[e];
            ah[e] = h0; al[e] = (half_t)((a0[e] - (float)h0) * 4096.0f);
            half_t h1 = (half_t)a1[e];
            ah[4+e] = h1; al[4+e] = (half_t)((a1[e] - (float)h1) * 4096.0f);
        }
#pragma unroll
        for (int nt = 0; nt < NT; ++nt) {
            half8 wh = *(const half8*)(WhF + pB[nt] + ks * 512 + lane8);
            half8 wl = *(const half8*)(WlF + pB[nt] + ks * 512 + lane8);
            Chi[nt] = __builtin_amdgcn_mfma_f32_16x16x32_f16(ah, wh, Chi[nt], 0, 0, 0);
            Clo[nt] = __builtin_amdgcn_mfma_f32_16x16x32_f16(ah, wl, Clo[nt], 0, 0, 0);
            Clo[nt] = __builtin_amdgcn_mfma_f32_16x16x32_f16(al, wh, Clo[nt], 0, 0, 0);
        }
    }
}

__global__ __launch_bounds__(1024)
void k4_tail(const float* __restrict__ S,
             const float* __restrict__ x,
             const float* __restrict__ h0,
             const float* __restrict__ c0,
             const half_t* __restrict__ tail,
             const float* __restrict__ bf3,
             const float* __restrict__ bg1, const float* __restrict__ bg2,
             const float* __restrict__ bg3,
             const float* __restrict__ b_ih, const float* __restrict__ b_hh,
             const float* __restrict__ bo1, const float* __restrict__ bo2,
             float* __restrict__ out,
             float* __restrict__ hid_out,
             float* __restrict__ h_out,
             float* __restrict__ c_out) {
    __shared__ float bufA[16 * AST];
    __shared__ float bufB[16 * AST];
    __shared__ float bufC[16 * AST];
    __shared__ float gt[16][512];
    const int tid = threadIdx.x;
    const int lane = tid & 63;
    const int w = tid >> 6;            // 0..15
    const int l15 = lane & 15;
    const int g4 = lane >> 4;
    const int r0 = blockIdx.x * 16;
    const int lane8 = lane * 8;

    for (int q = tid; q < 16 * 256; q += 1024)
        bufC[(q >> 8) * AST + (q & 255)] = S[(size_t)(r0 + (q >> 8)) * 256 + (q & 255)];
    for (int q = tid; q < 16 * 128; q += 1024)
        bufA[(q >> 7) * AST + (q & 127)] = x[(r0 + (q >> 7)) * 128 + (q & 127)];
    __syncthreads();

    const float* aFrag;
    int pB[2];
    float4_t Chi[2], Clo[2];

    // ---- SM (N=128): waves 0-7 ----
    if (w < 8) {
        const int n = w * 16 + l15;
        pB[0] = w * 4096;
        Chi[0] = float4_t{0,0,0,0}; Clo[0] = float4_t{0,0,0,0};
        aFrag = bufC + l15 * AST + g4 * 8;
        frag_gemm<1, 8>(aFrag, tail + T3H, tail + T3H + 32768, pB, lane8, Chi, Clo);
        const float b = 512.0f * bf3[n];
#pragma unroll
        for (int r = 0; r < 4; ++r)
            bufA[(g4 * 4 + r) * AST + 128 + n] = Chi[0][r] + Clo[0][r] * HL_INV + b;
    }
    __syncthreads();

    // ---- g1 (N=256): 16 waves, NT=1 ----
    {
        const int n = w * 16 + l15;
        pB[0] = w * 4096;
        Chi[0] = float4_t{0,0,0,0}; Clo[0] = float4_t{0,0,0,0};
        aFrag = bufA + l15 * AST + g4 * 8;
        frag_gemm<1, 8>(aFrag, tail + G1H, tail + G1H + 65536, pB, lane8, Chi, Clo);
        const float b = bg1[n];
#pragma unroll
        for (int r = 0; r < 4; ++r)
            bufB[(g4 * 4 + r) * AST + n] = fmaxf(Chi[0][r] + Clo[0][r] * HL_INV + b, 0.0f);
    }
    __syncthreads();

    // ---- g2 (N=256): 16 waves, NT=1 (+ stage h0) ----
    {
        const int n = w * 16 + l15;
        pB[0] = w * 4096;
        Chi[0] = float4_t{0,0,0,0}; Clo[0] = float4_t{0,0,0,0};
        aFrag = bufB + l15 * AST + g4 * 8;
        frag_gemm<1, 8>(aFrag, tail + G2H, tail + G2H + 65536, pB, lane8, Chi, Clo);
        const float b = bg2[n];
#pragma unroll
        for (int r = 0; r < 4; ++r)
            bufC[(g4 * 4 + r) * AST + n] = fmaxf(Chi[0][r] + Clo[0][r] * HL_INV + b, 0.0f);
        for (int q = tid; q < 16 * 128; q += 1024)
            bufA[(q >> 7) * AST + 128 + (q & 127)] = h0[(r0 + (q >> 7)) * 128 + (q & 127)];
    }
    __syncthreads();

    // ---- g3 (N=128): waves 0-7 ----
    if (w < 8) {
        const int n = w * 16 + l15;
        pB[0] = w * 4096;
        Chi[0] = float4_t{0,0,0,0}; Clo[0] = float4_t{0,0,0,0};
        aFrag = bufC + l15 * AST + g4 * 8;
        frag_gemm<1, 8>(aFrag, tail + G3H, tail + G3H + 32768, pB, lane8, Chi, Clo);
        const float b = bg3[n];
#pragma unroll
        for (int r = 0; r < 4; ++r)
            bufA[(g4 * 4 + r) * AST + n] = Chi[0][r] + Clo[0][r] * HL_INV + b;
    }
    __syncthreads();

    // ---- gates (N=512): 16 waves, NT=2 -> gt LDS ----
    {
#pragma unroll
        for (int nt = 0; nt < 2; ++nt) {
            pB[nt] = (w * 2 + nt) * 4096;
            Chi[nt] = float4_t{0,0,0,0}; Clo[nt] = float4_t{0,0,0,0};
        }
        aFrag = bufA + l15 * AST + g4 * 8;
        frag_gemm<2, 8>(aFrag, tail + CATH, tail + CATH + 131072, pB, lane8, Chi, Clo);
#pragma unroll
        for (int nt = 0; nt < 2; ++nt) {
            const int n = w * 32 + nt * 16 + l15;
            const float b = b_ih[n] + b_hh[n];
#pragma unroll
            for (int r = 0; r < 4; ++r)
                gt[g4 * 4 + r][n] = Chi[nt][r] + Clo[nt][r] * HL_INV + b;
        }
    }
    __syncthreads();

    // ---- LSTM elementwise: 1024 threads x 2 (row, nh) each ----
    {
        const int nh = tid & 127;
        const int rb = tid >> 7;       // 0..7
#pragma unroll
        for (int rr = 0; rr < 2; ++rr) {
            const int r = rb + rr * 8;
            const int row = r0 + r;
            float gi = sigmoidf_(gt[r][nh]);
            float gf = sigmoidf_(gt[r][128 + nh]);
            float gg = tanhf(    gt[r][256 + nh]);
            float go = sigmoidf_(gt[r][384 + nh]);
            float c = gf * c0[row * 128 + nh] + gi * gg;
            float h = go * tanhf(c);
            bufC[r * AST + nh] = h;
            hid_out[row * 128 + nh] = h;
            h_out[row * 128 + nh]   = h;
            c_out[row * 128 + nh]   = c;
        }
    }
    __syncthreads();

    // ---- o1 (N=256, K=128): 16 waves, NT=1 ----
    {
        const int n = w * 16 + l15;
        pB[0] = w * 2048;
        Chi[0] = float4_t{0,0,0,0}; Clo[0] = float4_t{0,0,0,0};
        aFrag = bufC + l15 * AST + g4 * 8;
        frag_gemm<1, 4>(aFrag, tail + O1H, tail + O1H + 32768, pB, lane8, Chi, Clo);
        const float b = bo1[n];
#pragma unroll
        for (int r = 0; r < 4; ++r)
            bufB[(g4 * 4 + r) * AST + n] = fmaxf(Chi[0][r] + Clo[0][r] * HL_INV + b, 0.0f);
    }
    __syncthreads();

    // ---- o2 (N=64): waves 0-3 ----
    if (w < 4) {
        const int n = w * 16 + l15;
        pB[0] = w * 4096;
        Chi[0] = float4_t{0,0,0,0}; Clo[0] = float4_t{0,0,0,0};
        aFrag = bufB + l15 * AST + g4 * 8;
        frag_gemm<1, 8>(aFrag, tail + O2H, tail + O2H + 16384, pB, lane8, Chi, Clo);
        const float b = bo2[n];
#pragma unroll
        for (int r = 0; r < 4; ++r)
            out[(r0 + g4 * 4 + r) * OUTD + n] = Chi[0][r] + Clo[0][r] * HL_INV + b;
    }
}

// ---------------------------------------------------------------------------
extern "C" void kernel_launch(void* const* d_in, const int* in_sizes, int n_in,
                              void* d_out, int out_size, void* d_ws, size_t ws_size,
                              hipStream_t stream) {
    const float* x      = (const float*)d_in[0];
    const float* hidden = (const float*)d_in[1];
    const float* h0     = (const float*)d_in[2];
    const float* c0     = (const float*)d_in[3];
    const float* Wf1    = (const float*)d_in[4];
    const float* bf1    = (const float*)d_in[5];
    const float* Wf2    = (const float*)d_in[6];
    const float* bf2    = (const float*)d_in[7];
    const float* Wf3    = (const float*)d_in[8];
    const float* bf3    = (const float*)d_in[9];
    const float* Wg1    = (const float*)d_in[10];
    const float* bg1    = (const float*)d_in[11];
    const float* Wg2    = (const float*)d_in[12];
    const float* bg2    = (const float*)d_in[13];
    const float* Wg3    = (const float*)d_in[14];
    const float* bg3    = (const float*)d_in[15];
    const float* W_ih   = (const float*)d_in[16];
    const float* W_hh   = (const float*)d_in[17];
    const float* b_ih   = (const float*)d_in[18];
    const float* b_hh   = (const float*)d_in[19];
    const float* Wo1    = (const float*)d_in[20];
    const float* bo1    = (const float*)d_in[21];
    const float* Wo2    = (const float*)d_in[22];
    const float* bo2    = (const float*)d_in[23];

    char* wsb = (char*)d_ws;
    float*  A32  = (float*)(wsb + 0);
    float*  B32  = (float*)(wsb + 524288);
    half_t* W2H  = (half_t*)(wsb + 1048576);
    half_t* W2L  = (half_t*)(wsb + 1179648);
    float*  S    = (float*)(wsb + 1310720);
    half_t* tail = (half_t*)(wsb + WS_TAIL_B);

    float* outp  = (float*)d_out;              // [512,64]
    float* hid1  = (float*)d_out + 32768;      // hidden_new [512,128]
    float* hid2  = (float*)d_out + 98304;      // hidden_new[None]
    float* cout  = (float*)d_out + 163840;     // c_new[None]

    kP_prep<<<dim3(61), dim3(1024), 0, stream>>>(hidden, Wf1, bf1, Wf2,
                                                 Wf3, Wg1, Wg2, Wg3,
                                                 W_ih, W_hh, Wo1, Wo2,
                                                 tail, W2H, W2L,
                                                 A32, B32, S);

    k2_pairwise<<<dim3(8, 32), dim3(512), 0, stream>>>(A32, B32, W2H, W2L, bf2, S);

    k4_tail<<<dim3(32), dim3(1024), 0, stream>>>(S, x, h0, c0, tail,
                                                 bf3, bg1, bg2, bg3,
                                                 b_ih, b_hh, bo1, bo2,
                                                 outp, hid1, hid2, cout);
}